// Round 7
// baseline (668.142 us; speedup 1.0000x reference)
//
#include <hip/hip_runtime.h>
#include <hip/hip_bf16.h>
#include <math.h>

// B=16,S=1024 -> M=16384 tokens; D=1024, F=4096, E=8, R=32, SCALING=0.5
// All four GEMMs use one m97-style 2-barrier kernel, BK=64: per K-iter
// {stage 2 k-blocks via global_load_lds; sync; 2x(ds_read+16 MFMA); sync}.
// Multi-block-per-CU occupancy provides overlap (m114). TM=128 for the
// big GEMMs, TM=64 for the LoRA-A GEMMs (2x grid for latency hiding).
// Operands in PACKED layout: each 256-row x 32-col block is contiguous
// 16KB with bank swizzle baked in: short_off(r,c) = r*32 + (c^((r&8)<<1));
// staging is a verbatim contiguous copy (1KiB per instruction), fragment
// reads conflict-free (PMC 0). LoRA-B folded into K:
// GEMM1 [M,1280]x[4096,1280]^T, GEMM2 [M,4352]x[1024,4352]^T.

#define M_TOK 16384
#define DIM_D 1024
#define DIM_F 4096
#define NEXP 8
#define RANK 32
#define NER 256   // NEXP*RANK
#define K1 1280   // DIM_D + NER
#define K2 4352   // DIM_F + NER

typedef __attribute__((ext_vector_type(8))) short bf16x8;
typedef __attribute__((ext_vector_type(4))) short sh4;
typedef __attribute__((ext_vector_type(4))) float f32x4;

__device__ inline short f2bs(float x) {
  __hip_bfloat16 h = __float2bfloat16(x);
  return *reinterpret_cast<short*>(&h);
}

__device__ inline void async16(const void* g, void* l) {
  __builtin_amdgcn_global_load_lds(
      (__attribute__((address_space(1))) void*)(g),
      (__attribute__((address_space(3))) void*)(l), 16, 0, 0);
}

// packed-layout helpers: blk = 256x32 tile index, off = swizzled offset
//   blk  = (row>>8)*(KP>>5) + (k>>5)
//   off  = (row&255)*32 + ((k&31) ^ ((row&8)<<1))        [shorts]
__device__ inline size_t pk_blk(int row, int k, int KP) {
  return (size_t)(row >> 8) * (KP >> 5) + (k >> 5);
}
__device__ inline int pk_off(int row, int k) {
  return (row & 255) * 32 + ((k & 31) ^ ((row & 8) << 1));
}

// ---------- fp32 [rows,C] -> packed bf16 (KP-pitch), 8 cols/thread ----------
__global__ __launch_bounds__(256) void convert_packed(
    const float* __restrict__ in, short* __restrict__ out,
    int c8, int KP, int n8)
{
  const int i = blockIdx.x * 256 + threadIdx.x;
  if (i >= n8) return;
  const int row = i / c8;
  const int k = (i % c8) * 8;
  const float4* p = (const float4*)(in + (size_t)row * (c8 * 8) + k);
  float4 u = p[0], v = p[1];
  bf16x8 r;
  r[0] = f2bs(u.x); r[1] = f2bs(u.y); r[2] = f2bs(u.z); r[3] = f2bs(u.w);
  r[4] = f2bs(v.x); r[5] = f2bs(v.y); r[6] = f2bs(v.z); r[7] = f2bs(v.w);
  *(bf16x8*)(out + pk_blk(row, k, KP) * 8192 + pk_off(row, k)) = r;
}

// ---------- LoRA-B [E,Nn,R] fp32 -> packed bf16 at k = ooff+e*32 ----------
__global__ __launch_bounds__(256) void pack_lorab(
    const float* __restrict__ in, short* __restrict__ out,
    int Nn, int KP, int ooff, int n8)
{
  const int i = blockIdx.x * 256 + threadIdx.x;
  if (i >= n8) return;
  const int e = i / (Nn * 4);
  const int rem = i % (Nn * 4);
  const int n = rem >> 2;
  const int r8 = (rem & 3) * 8;
  const int k = ooff + e * RANK + r8;
  const float4* p = (const float4*)(in + ((size_t)e * Nn + n) * RANK + r8);
  float4 u = p[0], v = p[1];
  bf16x8 r;
  r[0] = f2bs(u.x); r[1] = f2bs(u.y); r[2] = f2bs(u.z); r[3] = f2bs(u.w);
  r[4] = f2bs(v.x); r[5] = f2bs(v.y); r[6] = f2bs(v.z); r[7] = f2bs(v.w);
  *(bf16x8*)(out + pk_blk(n, k, KP) * 8192 + pk_off(n, k)) = r;
}

// ---------- router (one wave per token) + fused x->bf16 into packed xbw ----
__global__ __launch_bounds__(256) void router_kernel(
    const float* __restrict__ X,     // [M, D]
    const float* __restrict__ RW,    // [E, D]
    const float* __restrict__ RB,    // [E]
    float* __restrict__ routing_out, // [M, E]
    float* __restrict__ ec_out,      // [M, E]
    int* __restrict__ idx_out,       // [M]
    short* __restrict__ XB)          // packed [M, K1] bf16, cols 0..1023
{
  const int wave = threadIdx.x >> 6;
  const int lane = threadIdx.x & 63;
  const int t = blockIdx.x * 4 + wave;

  const float4* xp = (const float4*)(X + (size_t)t * DIM_D);
  float4 xv[4];
#pragma unroll
  for (int i = 0; i < 4; ++i) xv[i] = xp[lane + 64 * i];

#pragma unroll
  for (int i = 0; i < 4; ++i) {
    sh4 o;
    o[0] = f2bs(xv[i].x); o[1] = f2bs(xv[i].y);
    o[2] = f2bs(xv[i].z); o[3] = f2bs(xv[i].w);
    const int k0 = (lane + 64 * i) * 4;
    *(sh4*)&XB[pk_blk(t, k0, K1) * 8192 + pk_off(t, k0)] = o;
  }

  float logit[NEXP];
#pragma unroll
  for (int e = 0; e < NEXP; ++e) {
    const float4* wp = (const float4*)(RW + (size_t)e * DIM_D);
    double p = 0.0;
#pragma unroll
    for (int i = 0; i < 4; ++i) {
      float4 w = wp[lane + 64 * i];
      p += (double)xv[i].x * w.x + (double)xv[i].y * w.y +
           (double)xv[i].z * w.z + (double)xv[i].w * w.w;
    }
#pragma unroll
    for (int off = 32; off > 0; off >>= 1) p += __shfl_xor(p, off);
    logit[e] = (float)p + RB[e];
  }
  float m = logit[0];
  int am = 0;
#pragma unroll
  for (int e = 1; e < NEXP; ++e)
    if (logit[e] > m) { m = logit[e]; am = e; }
  float pr[NEXP], s = 0.f;
#pragma unroll
  for (int e = 0; e < NEXP; ++e) { pr[e] = expf(logit[e] - m); s += pr[e]; }
  const float inv = 1.f / s;
  if (lane < NEXP) {
    float r = pr[lane] * inv;
    routing_out[(size_t)t * NEXP + lane] = r;
    float y = (lane == am) ? 1.f : 0.f;
    ec_out[(size_t)t * NEXP + lane] = (y - r) + r;
  }
  if (lane == 0) idx_out[t] = am;
}

// ---------- unified TMx128 GEMM, C = A[M,KB] * Bm[N,KB]^T ----------
// A packed pitch KA (reads cols 0..KB-1), Bm packed pitch KB. BK=64
// (two 32-col k-blocks per iter), 4 waves (2x2), single-buffer LDS,
// 2 __syncthreads per iter; overlap from multi-block occupancy.
// EPI: 0 = acc+bias+0.5*LB[e]         -> fp32 row-major pitch OPK
//      1 = gelu(acc+bias+0.5*LB[e])   -> packed bf16 pitch OPK at col OOFF
//      2 = mask-by-idx 0.5*(acc+bias) -> packed bf16 pitch OPK at col OOFF
template <int TM, int KA, int KB, int N, int OPK, int OOFF, int EPI>
__global__ __launch_bounds__(256, 4) void gemmT(
    const short* __restrict__ A, const short* __restrict__ Bm,
    const float* __restrict__ LB, const float* __restrict__ bias,
    const int* __restrict__ idx, void* __restrict__ outv)
{
  static_assert(TM == 64 || TM == 128, "TM");
  constexpr int NA = TM / 32;       // A-frags per wave per k-slice
  __shared__ __align__(16) short As[TM * 64];   // 2 k-blocks of TM x 32
  __shared__ __align__(16) short Bs[128 * 64];  // 2 k-blocks of 128 x 32

  const int tid = threadIdx.x;
  const int lane = tid & 63;
  const int wv = tid >> 6;
  const int quad = lane >> 4;
  const int lrow = lane & 15;
  const int wr = wv >> 1;
  const int wc = wv & 1;
  const int swz = (quad * 8) ^ ((lrow & 8) << 1);

  // T1: XCD swizzle (nwg % 8 == 0 for all grids); n-major within XCD
  const int gx = gridDim.x;
  int id = blockIdx.y * gx + blockIdx.x;
  const int nwg = gx * gridDim.y;
  id = (id & 7) * (nwg >> 3) + (id >> 3);
  const int m0 = (id / gx) * TM;
  const int n0 = (id % gx) * 128;

  f32x4 acc[NA][4];
#pragma unroll
  for (int i = 0; i < NA; ++i)
#pragma unroll
    for (int j = 0; j < 4; ++j) acc[i][j] = (f32x4){0.f, 0.f, 0.f, 0.f};

  // packed k-block bases (advance by 8192 shorts per 32-col block)
  const short* Ab = A + ((size_t)(m0 >> 8) * (KA >> 5)) * 8192 +
                    (size_t)(m0 & 255) * 32 + tid * 8;
  const short* Bb = Bm + ((size_t)(n0 >> 8) * (KB >> 5)) * 8192 +
                    (size_t)(n0 & 255) * 32 + tid * 8;

  for (int it = 0; it < KB / 64; ++it) {
#pragma unroll
    for (int kb = 0; kb < 2; ++kb) {
      if constexpr (TM == 128) {
        async16(Ab, &As[kb * 4096 + tid * 8]);
        async16(Ab + 2048, &As[kb * 4096 + tid * 8 + 2048]);
      } else {
        async16(Ab, &As[kb * 2048 + tid * 8]);
      }
      async16(Bb, &Bs[kb * 4096 + tid * 8]);
      async16(Bb + 2048, &Bs[kb * 4096 + tid * 8 + 2048]);
      Ab += 8192;
      Bb += 8192;
    }
    __syncthreads();  // drains async copies (compiler-inserted vmcnt)

#pragma unroll
    for (int ks = 0; ks < 2; ++ks) {
      bf16x8 af[NA], bfv[4];
#pragma unroll
      for (int i = 0; i < NA; ++i)
        af[i] = *(const bf16x8*)&As[ks * (TM * 32) +
                                    (wr * (TM / 2) + i * 16 + lrow) * 32 + swz];
#pragma unroll
      for (int j = 0; j < 4; ++j)
        bfv[j] = *(const bf16x8*)&Bs[ks * 4096 +
                                     (wc * 64 + j * 16 + lrow) * 32 + swz];
#pragma unroll
      for (int i = 0; i < NA; ++i)
#pragma unroll
        for (int j = 0; j < 4; ++j)
          acc[i][j] = __builtin_amdgcn_mfma_f32_16x16x32_bf16(
              af[i], bfv[j], acc[i][j], 0, 0, 0);
    }
    __syncthreads();  // LDS reads done before next overwrite
  }

  // epilogue: C row = quad*4+reg, col = lrow (dtype-independent C/D map)
  float cb[4];
#pragma unroll
  for (int j = 0; j < 4; ++j) cb[j] = bias[n0 + wc * 64 + j * 16 + lrow];

#pragma unroll
  for (int i = 0; i < NA; ++i) {
#pragma unroll
    for (int reg = 0; reg < 4; ++reg) {
      const int t = m0 + wr * (TM / 2) + i * 16 + quad * 4 + reg;
      const int e = idx[t];
#pragma unroll
      for (int j = 0; j < 4; ++j) {
        const int gc = n0 + wc * 64 + j * 16 + lrow;
        if (EPI == 2) {
          float v = ((gc >> 5) == e) ? 0.5f * (acc[i][j][reg] + cb[j]) : 0.f;
          const int k = OOFF + gc;
          ((short*)outv)[pk_blk(t, k, OPK) * 8192 + pk_off(t, k)] = f2bs(v);
        } else {
          float v = acc[i][j][reg] + cb[j] + 0.5f * LB[(size_t)e * N + gc];
          if (EPI == 1) {
            v = 0.5f * v * (1.0f + erff(v * 0.70710678118654752f));
            const int k = OOFF + gc;
            ((short*)outv)[pk_blk(t, k, OPK) * 8192 + pk_off(t, k)] = f2bs(v);
          } else {
            ((float*)outv)[(size_t)t * OPK + gc] = v;
          }
        }
      }
    }
  }
}

extern "C" void kernel_launch(void* const* d_in, const int* in_sizes, int n_in,
                              void* d_out, int out_size, void* d_ws, size_t ws_size,
                              hipStream_t stream) {
  (void)in_sizes; (void)n_in; (void)out_size; (void)ws_size;
  const float* x        = (const float*)d_in[0];
  const float* router_w = (const float*)d_in[1];
  const float* router_b = (const float*)d_in[2];
  const float* fc1_w    = (const float*)d_in[3];
  const float* fc1_b    = (const float*)d_in[4];
  const float* fc2_w    = (const float*)d_in[5];
  const float* fc2_b    = (const float*)d_in[6];
  const float* down_A_w = (const float*)d_in[7];   // [E,R,D]
  const float* down_A_b = (const float*)d_in[8];   // [E*R]
  const float* down_B_w = (const float*)d_in[9];   // [E,F,R]
  const float* down_B_b = (const float*)d_in[10];  // [E,F]
  const float* up_A_w   = (const float*)d_in[11];  // [E,R,F]
  const float* up_A_b   = (const float*)d_in[12];  // [E*R]
  const float* up_B_w   = (const float*)d_in[13];  // [E,D,R]
  const float* up_B_b   = (const float*)d_in[14];  // [E,D]

  // ws: idx | xbw pk[M,K1] | aw pk[M,K2] | B1w pk[F,K1] | B2w pk[D,K2] | dAb | uAb
  char* ws = (char*)d_ws;
  size_t off = 0;
  int* idxp  = (int*)ws;              off += (size_t)M_TOK * 4;
  short* xbw = (short*)(ws + off);    off += (size_t)M_TOK * K1 * 2;
  short* aw  = (short*)(ws + off);    off += (size_t)M_TOK * K2 * 2;
  short* B1w = (short*)(ws + off);    off += (size_t)DIM_F * K1 * 2;
  short* B2w = (short*)(ws + off);    off += (size_t)DIM_D * K2 * 2;
  short* dAb = (short*)(ws + off);    off += (size_t)NER * DIM_D * 2;
  short* uAb = (short*)(ws + off);    off += (size_t)NER * DIM_F * 2;

  float* out = (float*)d_out;
  float* routing = out + (size_t)M_TOK * DIM_D;
  float* ec = routing + (size_t)M_TOK * NEXP;

  // weight conversions / packing into packed-tile layouts
  convert_packed<<<2048, 256, 0, stream>>>(fc1_w, B1w, 128, K1, 524288);
  convert_packed<<<2048, 256, 0, stream>>>(fc2_w, B2w, 512, K2, 524288);
  convert_packed<<<128,  256, 0, stream>>>(down_A_w, dAb, 128, DIM_D, 32768);
  convert_packed<<<512,  256, 0, stream>>>(up_A_w,   uAb, 512, DIM_F, 131072);
  pack_lorab<<<512, 256, 0, stream>>>(down_B_w, B1w, DIM_F, K1, DIM_D, 131072);
  pack_lorab<<<128, 256, 0, stream>>>(up_B_w,   B2w, DIM_D, K2, DIM_F, 32768);

  // router (+ x -> packed bf16 into xbw cols 0..1023)
  router_kernel<<<M_TOK / 4, 256, 0, stream>>>(x, router_w, router_b, routing,
                                               ec, idxp, xbw);
  // LoRA-A down: xbw packed cols 1024..1279 = mask(0.5*(x.dA^T + b))
  gemmT<64, K1, DIM_D, NER, K1, DIM_D, 2>
      <<<dim3(2, M_TOK / 64), 256, 0, stream>>>(
          xbw, dAb, nullptr, down_A_b, idxp, xbw);
  // GEMM1: aw packed cols 0..4095 = gelu(xbw . B1w^T + fc1_b + 0.5*dB_b[e])
  gemmT<128, K1, K1, DIM_F, K2, 0, 1>
      <<<dim3(DIM_F / 128, M_TOK / 128), 256, 0, stream>>>(
          xbw, B1w, down_B_b, fc1_b, idxp, aw);
  // LoRA-A up: aw packed cols 4096..4351 = mask(0.5*(a.uA^T + b))
  gemmT<64, K2, DIM_F, NER, K2, DIM_F, 2>
      <<<dim3(2, M_TOK / 64), 256, 0, stream>>>(
          aw, uAb, nullptr, up_A_b, idxp, aw);
  // GEMM2: out = aw . B2w^T + fc2_b + 0.5*uB_b[e]  (fp32 row-major)
  gemmT<128, K2, K2, DIM_D, DIM_D, 0, 0>
      <<<dim3(DIM_D / 128, M_TOK / 128), 256, 0, stream>>>(
          aw, B2w, up_B_b, fc2_b, idxp, out);
}

// Round 8
// 617.383 us; speedup vs baseline: 1.0822x; 1.0822x over previous
//
#include <hip/hip_runtime.h>
#include <hip/hip_bf16.h>
#include <math.h>

// B=16,S=1024 -> M=16384 tokens; D=1024, F=4096, E=8, R=32, SCALING=0.5
// All four GEMMs use the m97-style 2-barrier kernel, BK=32: per K-iter
// {stage one 32-col k-block via global_load_lds; sync; ds_read+MFMA; sync}.
// Multi-block-per-CU occupancy provides overlap (m114). TM=128 for the big
// GEMMs (R6 config, measured 252us), TM=64 for the LoRA-A GEMMs (512
// blocks = 2/CU). Operands in PACKED layout: each 256-row x 32-col block
// is contiguous 16KB with bank swizzle baked in:
// short_off(r,c) = r*32 + (c ^ ((r&8)<<1)); staging is a verbatim
// contiguous copy (1KiB/instruction), fragment reads conflict-free
// (PMC 0). LoRA-B folded into K: GEMM1 [M,1280]x[4096,1280]^T,
// GEMM2 [M,4352]x[1024,4352]^T. All weight prep fused into one launch.

#define M_TOK 16384
#define DIM_D 1024
#define DIM_F 4096
#define NEXP 8
#define RANK 32
#define NER 256   // NEXP*RANK
#define K1 1280   // DIM_D + NER
#define K2 4352   // DIM_F + NER

typedef __attribute__((ext_vector_type(8))) short bf16x8;
typedef __attribute__((ext_vector_type(4))) short sh4;
typedef __attribute__((ext_vector_type(4))) float f32x4;

__device__ inline short f2bs(float x) {
  __hip_bfloat16 h = __float2bfloat16(x);
  return *reinterpret_cast<short*>(&h);
}

__device__ inline void async16(const void* g, void* l) {
  __builtin_amdgcn_global_load_lds(
      (__attribute__((address_space(1))) void*)(g),
      (__attribute__((address_space(3))) void*)(l), 16, 0, 0);
}

// packed-layout helpers: blk = 256x32 tile index, off = swizzled offset
//   blk  = (row>>8)*(KP>>5) + (k>>5)
//   off  = (row&255)*32 + ((k&31) ^ ((row&8)<<1))        [shorts]
__device__ inline size_t pk_blk(int row, int k, int KP) {
  return (size_t)(row >> 8) * (KP >> 5) + (k >> 5);
}
__device__ inline int pk_off(int row, int k) {
  return (row & 255) * 32 + ((k & 31) ^ ((row & 8) << 1));
}

// ---------- prep bodies ----------
// fp32 [rows,C] -> packed bf16 (KP-pitch), 8 cols/elem-index i
__device__ inline void conv_body(const float* __restrict__ in,
                                 short* __restrict__ out,
                                 int c8, int KP, int i)
{
  const int row = i / c8;
  const int k = (i % c8) * 8;
  const float4* p = (const float4*)(in + (size_t)row * (c8 * 8) + k);
  float4 u = p[0], v = p[1];
  bf16x8 r;
  r[0] = f2bs(u.x); r[1] = f2bs(u.y); r[2] = f2bs(u.z); r[3] = f2bs(u.w);
  r[4] = f2bs(v.x); r[5] = f2bs(v.y); r[6] = f2bs(v.z); r[7] = f2bs(v.w);
  *(bf16x8*)(out + pk_blk(row, k, KP) * 8192 + pk_off(row, k)) = r;
}

// LoRA-B [E,Nn,R] fp32 -> packed bf16 at k = ooff+e*32
__device__ inline void lorab_body(const float* __restrict__ in,
                                  short* __restrict__ out,
                                  int Nn, int KP, int ooff, int i)
{
  const int e = i / (Nn * 4);
  const int rem = i % (Nn * 4);
  const int n = rem >> 2;
  const int r8 = (rem & 3) * 8;
  const int k = ooff + e * RANK + r8;
  const float4* p = (const float4*)(in + ((size_t)e * Nn + n) * RANK + r8);
  float4 u = p[0], v = p[1];
  bf16x8 r;
  r[0] = f2bs(u.x); r[1] = f2bs(u.y); r[2] = f2bs(u.z); r[3] = f2bs(u.w);
  r[4] = f2bs(v.x); r[5] = f2bs(v.y); r[6] = f2bs(v.z); r[7] = f2bs(v.w);
  *(bf16x8*)(out + pk_blk(n, k, KP) * 8192 + pk_off(n, k)) = r;
}

// ---------- single fused weight-prep launch (block-range dispatch) ----------
// grid = 2048 + 2048 + 128 + 512 + 512 + 128 = 5376 blocks of 256
__global__ __launch_bounds__(256) void prep_all(
    const float* __restrict__ fc1_w, const float* __restrict__ fc2_w,
    const float* __restrict__ dA, const float* __restrict__ uA,
    const float* __restrict__ dB, const float* __restrict__ uB,
    short* __restrict__ B1w, short* __restrict__ B2w,
    short* __restrict__ dAb, short* __restrict__ uAb)
{
  const int b = blockIdx.x;
  const int t = threadIdx.x;
  if (b < 2048)      conv_body(fc1_w, B1w, 128, K1, b * 256 + t);
  else if (b < 4096) conv_body(fc2_w, B2w, 512, K2, (b - 2048) * 256 + t);
  else if (b < 4224) conv_body(dA, dAb, 128, DIM_D, (b - 4096) * 256 + t);
  else if (b < 4736) conv_body(uA, uAb, 512, DIM_F, (b - 4224) * 256 + t);
  else if (b < 5248) lorab_body(dB, B1w, DIM_F, K1, DIM_D, (b - 4736) * 256 + t);
  else               lorab_body(uB, B2w, DIM_D, K2, DIM_F, (b - 5248) * 256 + t);
}

// ---------- router (one wave per token) + fused x->bf16 into packed xbw ----
__global__ __launch_bounds__(256) void router_kernel(
    const float* __restrict__ X,     // [M, D]
    const float* __restrict__ RW,    // [E, D]
    const float* __restrict__ RB,    // [E]
    float* __restrict__ routing_out, // [M, E]
    float* __restrict__ ec_out,      // [M, E]
    int* __restrict__ idx_out,       // [M]
    short* __restrict__ XB)          // packed [M, K1] bf16, cols 0..1023
{
  const int wave = threadIdx.x >> 6;
  const int lane = threadIdx.x & 63;
  const int t = blockIdx.x * 4 + wave;

  const float4* xp = (const float4*)(X + (size_t)t * DIM_D);
  float4 xv[4];
#pragma unroll
  for (int i = 0; i < 4; ++i) xv[i] = xp[lane + 64 * i];

#pragma unroll
  for (int i = 0; i < 4; ++i) {
    sh4 o;
    o[0] = f2bs(xv[i].x); o[1] = f2bs(xv[i].y);
    o[2] = f2bs(xv[i].z); o[3] = f2bs(xv[i].w);
    const int k0 = (lane + 64 * i) * 4;
    *(sh4*)&XB[pk_blk(t, k0, K1) * 8192 + pk_off(t, k0)] = o;
  }

  float logit[NEXP];
#pragma unroll
  for (int e = 0; e < NEXP; ++e) {
    const float4* wp = (const float4*)(RW + (size_t)e * DIM_D);
    double p = 0.0;
#pragma unroll
    for (int i = 0; i < 4; ++i) {
      float4 w = wp[lane + 64 * i];
      p += (double)xv[i].x * w.x + (double)xv[i].y * w.y +
           (double)xv[i].z * w.z + (double)xv[i].w * w.w;
    }
#pragma unroll
    for (int off = 32; off > 0; off >>= 1) p += __shfl_xor(p, off);
    logit[e] = (float)p + RB[e];
  }
  float m = logit[0];
  int am = 0;
#pragma unroll
  for (int e = 1; e < NEXP; ++e)
    if (logit[e] > m) { m = logit[e]; am = e; }
  float pr[NEXP], s = 0.f;
#pragma unroll
  for (int e = 0; e < NEXP; ++e) { pr[e] = expf(logit[e] - m); s += pr[e]; }
  const float inv = 1.f / s;
  if (lane < NEXP) {
    float r = pr[lane] * inv;
    routing_out[(size_t)t * NEXP + lane] = r;
    float y = (lane == am) ? 1.f : 0.f;
    ec_out[(size_t)t * NEXP + lane] = (y - r) + r;
  }
  if (lane == 0) idx_out[t] = am;
}

// ---------- unified TMx128 GEMM, C = A[M,KB] * Bm[N,KB]^T ----------
// A packed pitch KA (reads cols 0..KB-1), Bm packed pitch KB. BK=32
// (R6 config), 4 waves (2x2), single-buffer LDS, 2 __syncthreads per
// iter; overlap from multi-block occupancy (m114).
// EPI: 0 = acc+bias+0.5*LB[e]         -> fp32 row-major pitch OPK
//      1 = gelu(acc+bias+0.5*LB[e])   -> packed bf16 pitch OPK at col OOFF
//      2 = mask-by-idx 0.5*(acc+bias) -> packed bf16 pitch OPK at col OOFF
template <int TM, int KA, int KB, int N, int OPK, int OOFF, int EPI>
__global__ __launch_bounds__(256, 4) void gemmT(
    const short* __restrict__ A, const short* __restrict__ Bm,
    const float* __restrict__ LB, const float* __restrict__ bias,
    const int* __restrict__ idx, void* __restrict__ outv)
{
  static_assert(TM == 64 || TM == 128, "TM");
  constexpr int NA = TM / 32;       // A-frags per wave
  __shared__ __align__(16) short As[TM * 32];
  __shared__ __align__(16) short Bs[128 * 32];

  const int tid = threadIdx.x;
  const int lane = tid & 63;
  const int wv = tid >> 6;
  const int quad = lane >> 4;
  const int lrow = lane & 15;
  const int wr = wv >> 1;
  const int wc = wv & 1;
  const int swz = (quad * 8) ^ ((lrow & 8) << 1);

  // T1: XCD swizzle (nwg % 8 == 0 for all grids); n-major within XCD
  const int gx = gridDim.x;
  int id = blockIdx.y * gx + blockIdx.x;
  const int nwg = gx * gridDim.y;
  id = (id & 7) * (nwg >> 3) + (id >> 3);
  const int m0 = (id / gx) * TM;
  const int n0 = (id % gx) * 128;

  f32x4 acc[NA][4];
#pragma unroll
  for (int i = 0; i < NA; ++i)
#pragma unroll
    for (int j = 0; j < 4; ++j) acc[i][j] = (f32x4){0.f, 0.f, 0.f, 0.f};

  // packed k-block bases (advance by 8192 shorts per 32-col block)
  const short* Ab = A + ((size_t)(m0 >> 8) * (KA >> 5)) * 8192 +
                    (size_t)(m0 & 255) * 32 + tid * 8;
  const short* Bb = Bm + ((size_t)(n0 >> 8) * (KB >> 5)) * 8192 +
                    (size_t)(n0 & 255) * 32 + tid * 8;

  for (int it = 0; it < KB / 32; ++it) {
    if constexpr (TM == 128) {
      async16(Ab, &As[tid * 8]);
      async16(Ab + 2048, &As[tid * 8 + 2048]);
    } else {
      async16(Ab, &As[tid * 8]);  // 256 thr x 16B = 64x32 block exactly
    }
    async16(Bb, &Bs[tid * 8]);
    async16(Bb + 2048, &Bs[tid * 8 + 2048]);
    Ab += 8192;
    Bb += 8192;
    __syncthreads();  // drains async copies (compiler-inserted vmcnt)

    bf16x8 af[NA], bfv[4];
#pragma unroll
    for (int i = 0; i < NA; ++i)
      af[i] = *(const bf16x8*)&As[(wr * (TM / 2) + i * 16 + lrow) * 32 + swz];
#pragma unroll
    for (int j = 0; j < 4; ++j)
      bfv[j] = *(const bf16x8*)&Bs[(wc * 64 + j * 16 + lrow) * 32 + swz];
#pragma unroll
    for (int i = 0; i < NA; ++i)
#pragma unroll
      for (int j = 0; j < 4; ++j)
        acc[i][j] = __builtin_amdgcn_mfma_f32_16x16x32_bf16(af[i], bfv[j],
                                                            acc[i][j], 0, 0, 0);
    __syncthreads();  // LDS reads done before next overwrite
  }

  // epilogue: C row = quad*4+reg, col = lrow (dtype-independent C/D map)
  float cb[4];
#pragma unroll
  for (int j = 0; j < 4; ++j) cb[j] = bias[n0 + wc * 64 + j * 16 + lrow];

#pragma unroll
  for (int i = 0; i < NA; ++i) {
#pragma unroll
    for (int reg = 0; reg < 4; ++reg) {
      const int t = m0 + wr * (TM / 2) + i * 16 + quad * 4 + reg;
      const int e = idx[t];
#pragma unroll
      for (int j = 0; j < 4; ++j) {
        const int gc = n0 + wc * 64 + j * 16 + lrow;
        if (EPI == 2) {
          float v = ((gc >> 5) == e) ? 0.5f * (acc[i][j][reg] + cb[j]) : 0.f;
          const int k = OOFF + gc;
          ((short*)outv)[pk_blk(t, k, OPK) * 8192 + pk_off(t, k)] = f2bs(v);
        } else {
          float v = acc[i][j][reg] + cb[j] + 0.5f * LB[(size_t)e * N + gc];
          if (EPI == 1) {
            v = 0.5f * v * (1.0f + erff(v * 0.70710678118654752f));
            const int k = OOFF + gc;
            ((short*)outv)[pk_blk(t, k, OPK) * 8192 + pk_off(t, k)] = f2bs(v);
          } else {
            ((float*)outv)[(size_t)t * OPK + gc] = v;
          }
        }
      }
    }
  }
}

extern "C" void kernel_launch(void* const* d_in, const int* in_sizes, int n_in,
                              void* d_out, int out_size, void* d_ws, size_t ws_size,
                              hipStream_t stream) {
  (void)in_sizes; (void)n_in; (void)out_size; (void)ws_size;
  const float* x        = (const float*)d_in[0];
  const float* router_w = (const float*)d_in[1];
  const float* router_b = (const float*)d_in[2];
  const float* fc1_w    = (const float*)d_in[3];
  const float* fc1_b    = (const float*)d_in[4];
  const float* fc2_w    = (const float*)d_in[5];
  const float* fc2_b    = (const float*)d_in[6];
  const float* down_A_w = (const float*)d_in[7];   // [E,R,D]
  const float* down_A_b = (const float*)d_in[8];   // [E*R]
  const float* down_B_w = (const float*)d_in[9];   // [E,F,R]
  const float* down_B_b = (const float*)d_in[10];  // [E,F]
  const float* up_A_w   = (const float*)d_in[11];  // [E,R,F]
  const float* up_A_b   = (const float*)d_in[12];  // [E*R]
  const float* up_B_w   = (const float*)d_in[13];  // [E,D,R]
  const float* up_B_b   = (const float*)d_in[14];  // [E,D]

  // ws: idx | xbw pk[M,K1] | aw pk[M,K2] | B1w pk[F,K1] | B2w pk[D,K2] | dAb | uAb
  char* ws = (char*)d_ws;
  size_t off = 0;
  int* idxp  = (int*)ws;              off += (size_t)M_TOK * 4;
  short* xbw = (short*)(ws + off);    off += (size_t)M_TOK * K1 * 2;
  short* aw  = (short*)(ws + off);    off += (size_t)M_TOK * K2 * 2;
  short* B1w = (short*)(ws + off);    off += (size_t)DIM_F * K1 * 2;
  short* B2w = (short*)(ws + off);    off += (size_t)DIM_D * K2 * 2;
  short* dAb = (short*)(ws + off);    off += (size_t)NER * DIM_D * 2;
  short* uAb = (short*)(ws + off);    off += (size_t)NER * DIM_F * 2;

  float* out = (float*)d_out;
  float* routing = out + (size_t)M_TOK * DIM_D;
  float* ec = routing + (size_t)M_TOK * NEXP;

  // all weight conversions / packing in one launch
  prep_all<<<5376, 256, 0, stream>>>(fc1_w, fc2_w, down_A_w, up_A_w,
                                     down_B_w, up_B_w, B1w, B2w, dAb, uAb);

  // router (+ x -> packed bf16 into xbw cols 0..1023)
  router_kernel<<<M_TOK / 4, 256, 0, stream>>>(x, router_w, router_b, routing,
                                               ec, idxp, xbw);
  // LoRA-A down: xbw packed cols 1024..1279 = mask(0.5*(x.dA^T + b))
  gemmT<64, K1, DIM_D, NER, K1, DIM_D, 2>
      <<<dim3(2, M_TOK / 64), 256, 0, stream>>>(
          xbw, dAb, nullptr, down_A_b, idxp, xbw);
  // GEMM1: aw packed cols 0..4095 = gelu(xbw . B1w^T + fc1_b + 0.5*dB_b[e])
  gemmT<128, K1, K1, DIM_F, K2, 0, 1>
      <<<dim3(DIM_F / 128, M_TOK / 128), 256, 0, stream>>>(
          xbw, B1w, down_B_b, fc1_b, idxp, aw);
  // LoRA-A up: aw packed cols 4096..4351 = mask(0.5*(a.uA^T + b))
  gemmT<64, K2, DIM_F, NER, K2, DIM_F, 2>
      <<<dim3(2, M_TOK / 64), 256, 0, stream>>>(
          aw, uAb, nullptr, up_A_b, idxp, aw);
  // GEMM2: out = aw . B2w^T + fc2_b + 0.5*uB_b[e]  (fp32 row-major)
  gemmT<128, K2, K2, DIM_D, DIM_D, 0, 0>
      <<<dim3(DIM_D / 128, M_TOK / 128), 256, 0, stream>>>(
          aw, B2w, up_B_b, fc2_b, idxp, out);
}